// Round 16
// baseline (33027.380 us; speedup 1.0000x reference)
//
#include <hip/hip_runtime.h>
#include <cstdint>

// GRU persistent kernel v14: T=512, B=64, I=512, H=1024, O=512, fp32.
// == v9 (best: 13.6 ms; 256 blk x 512 thr, 128 VGPR, h-stash, 96 KB swizzled
// weights, sc0/sc1 fence-free coherent h/s exchange, relaxed 2-group barrier)
// with two targeted cuts:
//  1. NO x transpose: phase C reads x[t][b][k] directly, b-major mapping
//     (thread=(b, ksec), 32 contiguous k per thread -> coalesced 8KB/wave).
//     Removes the stride-512 gather transpose kernel + 64 MB workspace.
//  2. Phase C reduction fully in-wave (shfl_xor 1/2/4/8 over the 16 k-sections)
//     -> zero LDS reduce rounds, zero extra syncthreads in C.
// Phases per step:
//   P1: r = sigmoid(h@W_rh + xr_pre + b_r); s = r*h; stash h -> arrive(A)
//   A2: z = sigmoid(h@W_zh + xz_pre + b_z); y_{t-1}=h@Wout (from stash) -> wait(A)
//   P2: ht = tanh(s@W_hh + xh_pre + b_h); h += z*(ht-h)     -> arrive(B)
//   C : xr/xz/xh_pre for t+1 (direct x read, hides barrier B) -> wait(B)

#define TT 512
#define BB 64
#define II 512
#define HH 1024
#define OO 512
#define NTHR 512

typedef float4 f4;
__device__ __forceinline__ f4 ld4(const float* p){ return *reinterpret_cast<const f4*>(p); }
// k-swizzle for ksec-stride-16 LDS weight reads (v3/v9-verified: conflicts ~0)
__device__ __forceinline__ int swz(int k){ return k ^ (((k >> 4) & 7) << 2); }

// ---- coherent (L2-bypass, L3-served) access helpers for h/s ----
__device__ __forceinline__ void ldc16(const float* p, f4* d){
  asm volatile(
    "global_load_dwordx4 %0,  %16, off sc0 sc1\n\t"
    "global_load_dwordx4 %1,  %16, off offset:256 sc0 sc1\n\t"
    "global_load_dwordx4 %2,  %16, off offset:512 sc0 sc1\n\t"
    "global_load_dwordx4 %3,  %16, off offset:768 sc0 sc1\n\t"
    "global_load_dwordx4 %4,  %16, off offset:1024 sc0 sc1\n\t"
    "global_load_dwordx4 %5,  %16, off offset:1280 sc0 sc1\n\t"
    "global_load_dwordx4 %6,  %16, off offset:1536 sc0 sc1\n\t"
    "global_load_dwordx4 %7,  %16, off offset:1792 sc0 sc1\n\t"
    "global_load_dwordx4 %8,  %16, off offset:2048 sc0 sc1\n\t"
    "global_load_dwordx4 %9,  %16, off offset:2304 sc0 sc1\n\t"
    "global_load_dwordx4 %10, %16, off offset:2560 sc0 sc1\n\t"
    "global_load_dwordx4 %11, %16, off offset:2816 sc0 sc1\n\t"
    "global_load_dwordx4 %12, %16, off offset:3072 sc0 sc1\n\t"
    "global_load_dwordx4 %13, %16, off offset:3328 sc0 sc1\n\t"
    "global_load_dwordx4 %14, %16, off offset:3584 sc0 sc1\n\t"
    "s_waitcnt vmcnt(1)\n\t"
    "global_load_dwordx4 %15, %16, off offset:3840 sc0 sc1\n\t"
    "s_waitcnt vmcnt(0)"
    : "=&v"(d[0]),"=&v"(d[1]),"=&v"(d[2]),"=&v"(d[3]),
      "=&v"(d[4]),"=&v"(d[5]),"=&v"(d[6]),"=&v"(d[7]),
      "=&v"(d[8]),"=&v"(d[9]),"=&v"(d[10]),"=&v"(d[11]),
      "=&v"(d[12]),"=&v"(d[13]),"=&v"(d[14]),"=&v"(d[15])
    : "v"(p) : "memory");
}
__device__ __forceinline__ float ldc1(const float* p){
  float v;
  asm volatile("global_load_dword %0, %1, off sc0 sc1\n\ts_waitcnt vmcnt(0)"
               : "=v"(v) : "v"(p) : "memory");
  return v;
}
__device__ __forceinline__ void stc1(float* p, float v){
  asm volatile("global_store_dword %0, %1, off sc0 sc1" :: "v"(p), "v"(v) : "memory");
}

// ---------------- one-time prep kernels ----------------
__global__ void k_transpose_wx(const float* __restrict__ W, float* __restrict__ WT){
  size_t n = (size_t)blockIdx.x * blockDim.x + threadIdx.x;
  if (n >= (size_t)II * HH) return;
  size_t j = n / II, k = n % II;
  WT[n] = W[k * HH + j];
}

__global__ void k_transpose_h0(const float* __restrict__ st, float* __restrict__ h0){
  size_t n = (size_t)blockIdx.x * blockDim.x + threadIdx.x;
  if (n >= (size_t)HH * BB) return;
  size_t j = n / BB, b = n % BB;
  h0[n] = st[b * HH + j];
}

__global__ void k_init_bars(unsigned* bars){
  if (threadIdx.x < 512) bars[threadIdx.x] = 0;
}

// ------- barrier: per b-half group of 128 blocks; RELAXED atomics only -------
__device__ __forceinline__ void g_arrive(unsigned* bars, int g, int jt, unsigned ep){
  asm volatile("s_waitcnt vmcnt(0)" ::: "memory");
  unsigned* leaf = bars + (g * 9 + (jt & 7)) * 16;
  unsigned old = __hip_atomic_fetch_add(leaf, 1u, __ATOMIC_RELAXED, __HIP_MEMORY_SCOPE_AGENT);
  if (old + 1u == ep * 16u)
    __hip_atomic_fetch_add(bars + (g * 9 + 8) * 16, 1u, __ATOMIC_RELAXED, __HIP_MEMORY_SCOPE_AGENT);
}
__device__ __forceinline__ void g_wait(unsigned* bars, int g, unsigned ep){
  unsigned* root = bars + (g * 9 + 8) * 16;
  while (__hip_atomic_load(root, __ATOMIC_RELAXED, __HIP_MEMORY_SCOPE_AGENT) < ep * 8u)
    __builtin_amdgcn_s_sleep(1);
}

// shfl-reduce over the 3 ksec bits inside a wave (lanes 8,16,32)
#define WREDUCE(v) { v += __shfl_xor(v, 8); v += __shfl_xor(v, 16); v += __shfl_xor(v, 32); }

// ---------------- the persistent GRU kernel ----------------
__global__ __launch_bounds__(NTHR, 2) void k_gru(
    const float* __restrict__ x,
    const float* __restrict__ WxTr, const float* __restrict__ WxTz, const float* __restrict__ WxTh,
    float* __restrict__ h, float* __restrict__ s,
    const float* __restrict__ W_zh, const float* __restrict__ b_z,
    const float* __restrict__ W_rh, const float* __restrict__ b_r,
    const float* __restrict__ W_hh, const float* __restrict__ b_h,
    const float* __restrict__ W_out, const float* __restrict__ b_out,
    float* __restrict__ out, unsigned* __restrict__ bars)
{
  __shared__ float sW[3 * 8 * 1024];   // [0=RH,1=ZH,2=HH][c<8][k swz]  96 KB
  __shared__ float red[8 * 528];       // cross-wave reduce             16.9 KB
  __shared__ float xpre[3][256];       // x-projections (8c x 32b)
  __shared__ float sZ[256];            // z gate
  __shared__ float sBias[32];          // b_r[8] b_z[8] b_h[8] b_out[4]

  const int tid = threadIdx.x;
  const int bid = blockIdx.x;
  const int jt = bid & 127, bhalf = bid >> 7;
  const int j0 = jt * 8, o0 = jt * 4, bbase = bhalf * 32;

  // ---- prologue: weight slices -> swizzled LDS ----
  #pragma unroll
  for (int kk2 = 0; kk2 < 2; ++kk2){
    const int k = tid * 2 + kk2;           // 0..1023
    f4 vr  = ld4(W_rh + (size_t)k * HH + j0);
    f4 vr2 = ld4(W_rh + (size_t)k * HH + j0 + 4);
    f4 vz  = ld4(W_zh + (size_t)k * HH + j0);
    f4 vz2 = ld4(W_zh + (size_t)k * HH + j0 + 4);
    f4 vh  = ld4(W_hh + (size_t)k * HH + j0);
    f4 vh2 = ld4(W_hh + (size_t)k * HH + j0 + 4);
    const int kx = swz(k);
    float ar[8] = {vr.x,vr.y,vr.z,vr.w,vr2.x,vr2.y,vr2.z,vr2.w};
    float az[8] = {vz.x,vz.y,vz.z,vz.w,vz2.x,vz2.y,vz2.z,vz2.w};
    float ah[8] = {vh.x,vh.y,vh.z,vh.w,vh2.x,vh2.y,vh2.z,vh2.w};
    #pragma unroll
    for (int c = 0; c < 8; ++c){
      sW[0*8192 + c*1024 + kx] = ar[c];
      sW[1*8192 + c*1024 + kx] = az[c];
      sW[2*8192 + c*1024 + kx] = ah[c];
    }
  }
  if (tid < 8){
    sBias[tid]      = b_r[j0 + tid];
    sBias[8 + tid]  = b_z[j0 + tid];
    sBias[16 + tid] = b_h[j0 + tid];
    if (tid < 4) sBias[24 + tid] = b_out[o0 + tid];
  }

  const int bg = tid & 7, b0 = bbase + bg * 4;
  const int ksec = tid >> 3;           // 0..63
  const int wv = tid >> 6;             // wave 0..7
  const bool wr0 = ((tid & 56) == 0);
  const int kh0 = ksec * 16;           // K=1024 / 64

  // phase-C mapping (direct x): thread = (b-half row, 16 k-sections x 32 k)
  const int bC  = bbase + (tid >> 4);  // 32 rows of this b-half
  const int ksC = tid & 15;
  const int k0C = ksC * 32;
  __syncthreads();

  for (int t = -1; t < TT; ++t){
    f4 st4[16];                        // h stash, P1 -> A2
    if (t >= 0){
      // ================= P1: r gate =================
      float aR[8][4] = {};
      ldc16(h + kh0 * BB + b0, st4);   // coherent h read (16 k x 4 b)
      #pragma unroll
      for (int i4 = 0; i4 < 4; ++i4){
        const int kxc = swz(kh0 + i4*4);
        #pragma unroll
        for (int c = 0; c < 8; ++c){
          f4 wf = *reinterpret_cast<const f4*>(&sW[0*8192 + c*1024 + kxc]);
          float wvv[4] = {wf.x, wf.y, wf.z, wf.w};
          #pragma unroll
          for (int kk = 0; kk < 4; ++kk){
            const f4 hv = st4[i4*4+kk];
            aR[c][0] = fmaf(wvv[kk], hv.x, aR[c][0]);
            aR[c][1] = fmaf(wvv[kk], hv.y, aR[c][1]);
            aR[c][2] = fmaf(wvv[kk], hv.z, aR[c][2]);
            aR[c][3] = fmaf(wvv[kk], hv.w, aR[c][3]);
          }
        }
      }
      #pragma unroll
      for (int c = 0; c < 8; ++c)
        #pragma unroll
        for (int bb = 0; bb < 4; ++bb) WREDUCE(aR[c][bb]);
      if (wr0)
        #pragma unroll
        for (int c = 0; c < 8; ++c)
          #pragma unroll
          for (int bb = 0; bb < 4; ++bb)
            red[wv*528 + c*32 + bg*4 + bb] = aR[c][bb];
      __syncthreads();
      if (tid < 256){
        float sum = 0.f;
        #pragma unroll
        for (int w = 0; w < 8; ++w) sum += red[w*528 + tid];
        const int c = tid >> 5, bl = tid & 31;
        const float v = sum + xpre[0][tid] + sBias[c];
        const float rr = 1.f / (1.f + expf(-v));
        const int jg = j0 + c, bgl = bbase + bl;
        stc1(&s[jg*BB + bgl], rr * ldc1(&h[jg*BB + bgl]));
      }
      __syncthreads();
      if (tid == 0) g_arrive(bars, bhalf, jt, 2*t + 1);

      // ========== A2: z gate + y_{t-1} from stash (hides barrier A) ==========
      float aZ[8][4] = {};
      float aY[4][4] = {};
      #pragma unroll
      for (int i4 = 0; i4 < 4; ++i4){
        const int kc = kh0 + i4*4;
        const int kxc = swz(kc);
        #pragma unroll
        for (int c = 0; c < 8; ++c){
          f4 wf = *reinterpret_cast<const f4*>(&sW[1*8192 + c*1024 + kxc]);
          float wvv[4] = {wf.x, wf.y, wf.z, wf.w};
          #pragma unroll
          for (int kk = 0; kk < 4; ++kk){
            const f4 hv = st4[i4*4+kk];
            aZ[c][0] = fmaf(wvv[kk], hv.x, aZ[c][0]);
            aZ[c][1] = fmaf(wvv[kk], hv.y, aZ[c][1]);
            aZ[c][2] = fmaf(wvv[kk], hv.z, aZ[c][2]);
            aZ[c][3] = fmaf(wvv[kk], hv.w, aZ[c][3]);
          }
        }
        #pragma unroll
        for (int oc = 0; oc < 4; ++oc){
          f4 wo = ld4(W_out + (size_t)(o0 + oc) * HH + kc);   // L2-hot
          float wvv[4] = {wo.x, wo.y, wo.z, wo.w};
          #pragma unroll
          for (int kk = 0; kk < 4; ++kk){
            const f4 hv = st4[i4*4+kk];
            aY[oc][0] = fmaf(wvv[kk], hv.x, aY[oc][0]);
            aY[oc][1] = fmaf(wvv[kk], hv.y, aY[oc][1]);
            aY[oc][2] = fmaf(wvv[kk], hv.z, aY[oc][2]);
            aY[oc][3] = fmaf(wvv[kk], hv.w, aY[oc][3]);
          }
        }
      }
      #pragma unroll
      for (int c = 0; c < 8; ++c)
        #pragma unroll
        for (int bb = 0; bb < 4; ++bb) WREDUCE(aZ[c][bb]);
      #pragma unroll
      for (int oc = 0; oc < 4; ++oc)
        #pragma unroll
        for (int bb = 0; bb < 4; ++bb) WREDUCE(aY[oc][bb]);
      if (wr0){
        #pragma unroll
        for (int c = 0; c < 8; ++c)
          #pragma unroll
          for (int bb = 0; bb < 4; ++bb)
            red[wv*528 + c*32 + bg*4 + bb] = aZ[c][bb];
        #pragma unroll
        for (int oc = 0; oc < 4; ++oc)
          #pragma unroll
          for (int bb = 0; bb < 4; ++bb)
            red[wv*528 + 256 + oc*32 + bg*4 + bb] = aY[oc][bb];
      }
      __syncthreads();
      if (tid < 256){
        float sum = 0.f;
        #pragma unroll
        for (int w = 0; w < 8; ++w) sum += red[w*528 + tid];
        const int c = tid >> 5;
        sZ[tid] = 1.f / (1.f + expf(-(sum + xpre[1][tid] + sBias[8 + c])));
      } else if (tid < 384){
        const int idx = tid - 256;
        float sum = 0.f;
        #pragma unroll
        for (int w = 0; w < 8; ++w) sum += red[w*528 + tid];
        const int oc = idx >> 5, bl = idx & 31;
        if (t > 0)
          out[((size_t)(t-1)*BB + bbase + bl)*OO + o0 + oc] = sum + sBias[24 + oc];
      }
      if (tid == 0) g_wait(bars, bhalf, 2*t + 1);
      __syncthreads();

      // ================= P2: candidate + h update =================
      float aH[8][4] = {};
      f4 sv16[16];
      ldc16(s + kh0 * BB + b0, sv16);  // coherent s read
      #pragma unroll
      for (int i4 = 0; i4 < 4; ++i4){
        const int kxc = swz(kh0 + i4*4);
        #pragma unroll
        for (int c = 0; c < 8; ++c){
          f4 wf = *reinterpret_cast<const f4*>(&sW[2*8192 + c*1024 + kxc]);
          float wvv[4] = {wf.x, wf.y, wf.z, wf.w};
          #pragma unroll
          for (int kk = 0; kk < 4; ++kk){
            const f4 sv = sv16[i4*4+kk];
            aH[c][0] = fmaf(wvv[kk], sv.x, aH[c][0]);
            aH[c][1] = fmaf(wvv[kk], sv.y, aH[c][1]);
            aH[c][2] = fmaf(wvv[kk], sv.z, aH[c][2]);
            aH[c][3] = fmaf(wvv[kk], sv.w, aH[c][3]);
          }
        }
      }
      #pragma unroll
      for (int c = 0; c < 8; ++c)
        #pragma unroll
        for (int bb = 0; bb < 4; ++bb) WREDUCE(aH[c][bb]);
      if (wr0)
        #pragma unroll
        for (int c = 0; c < 8; ++c)
          #pragma unroll
          for (int bb = 0; bb < 4; ++bb)
            red[wv*528 + c*32 + bg*4 + bb] = aH[c][bb];
      __syncthreads();
      if (tid < 256){
        float sum = 0.f;
        #pragma unroll
        for (int w = 0; w < 8; ++w) sum += red[w*528 + tid];
        const int c = tid >> 5, bl = tid & 31;
        const int jg = j0 + c, bgl = bbase + bl;
        const float ht = tanhf(sum + xpre[2][tid] + sBias[16 + c]);
        const float z = sZ[tid];
        const float hold = ldc1(&h[jg*BB + bgl]);
        const float hnew = fmaf(z, ht - hold, hold);
        stc1(&h[jg*BB + bgl], hnew);
        if (t == TT - 1) out[(size_t)TT*BB*OO + (size_t)bgl*HH + jg] = hnew;
      }
      __syncthreads();
      if (tid == 0) g_arrive(bars, bhalf, jt, 2*t + 2);
    }

    // ==== C: x-projections for t+1, DIRECT x read, in-wave reduce ====
    if (t + 1 < TT){
      const int tc = t + 1;
      const float* xb = x + ((size_t)tc * BB + bC) * II + k0C;  // 32 contiguous k
      float aX[3][8];
      #pragma unroll
      for (int g = 0; g < 3; ++g)
        #pragma unroll
        for (int c = 0; c < 8; ++c) aX[g][c] = 0.f;
      #pragma unroll
      for (int i4 = 0; i4 < 8; ++i4){
        f4 xv = ld4(xb + i4*4);
        float xvv[4] = {xv.x, xv.y, xv.z, xv.w};
        #pragma unroll
        for (int c = 0; c < 8; ++c){
          f4 wr_ = ld4(WxTr + (size_t)(j0 + c) * II + k0C + i4*4);
          f4 wz_ = ld4(WxTz + (size_t)(j0 + c) * II + k0C + i4*4);
          f4 wh_ = ld4(WxTh + (size_t)(j0 + c) * II + k0C + i4*4);
          float wrv[4] = {wr_.x, wr_.y, wr_.z, wr_.w};
          float wzv[4] = {wz_.x, wz_.y, wz_.z, wz_.w};
          float whv[4] = {wh_.x, wh_.y, wh_.z, wh_.w};
          #pragma unroll
          for (int kk = 0; kk < 4; ++kk){
            aX[0][c] = fmaf(wrv[kk], xvv[kk], aX[0][c]);
            aX[1][c] = fmaf(wzv[kk], xvv[kk], aX[1][c]);
            aX[2][c] = fmaf(whv[kk], xvv[kk], aX[2][c]);
          }
        }
      }
      // in-wave reduce over the 4 ksC bits (lane bits 0..3)
      #pragma unroll
      for (int g = 0; g < 3; ++g)
        #pragma unroll
        for (int c = 0; c < 8; ++c){
          aX[g][c] += __shfl_xor(aX[g][c], 1);
          aX[g][c] += __shfl_xor(aX[g][c], 2);
          aX[g][c] += __shfl_xor(aX[g][c], 4);
          aX[g][c] += __shfl_xor(aX[g][c], 8);
        }
      if (ksC == 0){
        const int bl = bC - bbase;
        #pragma unroll
        for (int g = 0; g < 3; ++g)
          #pragma unroll
          for (int c = 0; c < 8; ++c)
            xpre[g][c*32 + bl] = aX[g][c];
      }
      __syncthreads();
    }

    if (t >= 0){
      if (tid == 0) g_wait(bars, bhalf, 2*t + 2);
      __syncthreads();
    }
  }

  // ================= trailing y_{T-1} from final h =================
  {
    float aY[4][4] = {};
    f4 hv16[16];
    ldc16(h + kh0 * BB + b0, hv16);
    #pragma unroll
    for (int i4 = 0; i4 < 4; ++i4){
      const int kc = kh0 + i4*4;
      #pragma unroll
      for (int oc = 0; oc < 4; ++oc){
        f4 wo = ld4(W_out + (size_t)(o0 + oc) * HH + kc);
        float wvv[4] = {wo.x, wo.y, wo.z, wo.w};
        #pragma unroll
        for (int kk = 0; kk < 4; ++kk){
          const f4 hv = hv16[i4*4+kk];
          aY[oc][0] = fmaf(wvv[kk], hv.x, aY[oc][0]);
          aY[oc][1] = fmaf(wvv[kk], hv.y, aY[oc][1]);
          aY[oc][2] = fmaf(wvv[kk], hv.z, aY[oc][2]);
          aY[oc][3] = fmaf(wvv[kk], hv.w, aY[oc][3]);
        }
      }
    }
    #pragma unroll
    for (int oc = 0; oc < 4; ++oc)
      #pragma unroll
      for (int bb = 0; bb < 4; ++bb) WREDUCE(aY[oc][bb]);
    if (wr0)
      #pragma unroll
      for (int oc = 0; oc < 4; ++oc)
        #pragma unroll
        for (int bb = 0; bb < 4; ++bb)
          red[wv*528 + oc*32 + bg*4 + bb] = aY[oc][bb];
    __syncthreads();
    if (tid < 128){
      float sum = 0.f;
      #pragma unroll
      for (int w = 0; w < 8; ++w) sum += red[w*528 + tid];
      const int oc = tid >> 5, bl = tid & 31;
      out[((size_t)(TT-1)*BB + bbase + bl)*OO + o0 + oc] = sum + sBias[24 + oc];
    }
  }
}

// ---------------- host ----------------
extern "C" void kernel_launch(void* const* d_in, const int* in_sizes, int n_in,
                              void* d_out, int out_size, void* d_ws, size_t ws_size,
                              hipStream_t stream) {
  const float* x     = (const float*)d_in[0];
  const float* st    = (const float*)d_in[1];
  const float* W_zh  = (const float*)d_in[2];
  const float* W_zx  = (const float*)d_in[3];
  const float* b_z   = (const float*)d_in[4];
  const float* W_rh  = (const float*)d_in[5];
  const float* W_rx  = (const float*)d_in[6];
  const float* b_r   = (const float*)d_in[7];
  const float* W_hh  = (const float*)d_in[8];
  const float* W_hx  = (const float*)d_in[9];
  const float* b_h   = (const float*)d_in[10];
  const float* W_out = (const float*)d_in[11];
  const float* b_out = (const float*)d_in[12];
  float* out = (float*)d_out;
  float* ws  = (float*)d_ws;

  const size_t wx_sz = (size_t)II * HH;        // 524,288
  const size_t h_sz  = (size_t)HH * BB;        //  65,536
  const size_t need  = (3*wx_sz + 2*h_sz) * sizeof(float) + 512*sizeof(unsigned);
  if (ws_size < need) return;

  float* WxTr = ws;
  float* WxTz = WxTr + wx_sz;
  float* WxTh = WxTz + wx_sz;
  float* h    = WxTh + wx_sz;
  float* s    = h + h_sz;
  unsigned* bars = (unsigned*)(s + h_sz);

  k_transpose_wx<<<2048, 256, 0, stream>>>(W_rx, WxTr);
  k_transpose_wx<<<2048, 256, 0, stream>>>(W_zx, WxTz);
  k_transpose_wx<<<2048, 256, 0, stream>>>(W_hx, WxTh);
  k_transpose_h0<<< 256, 256, 0, stream>>>(st, h);
  k_init_bars   <<<   1, 512, 0, stream>>>(bars);

  k_gru<<<256, NTHR, 0, stream>>>(x, WxTr, WxTz, WxTh, h, s,
                                  W_zh, b_z, W_rh, b_r, W_hh, b_h,
                                  W_out, b_out, out, bars);
}

// Round 17
// 24034.576 us; speedup vs baseline: 1.3742x; 1.3742x over previous
//
#include <hip/hip_runtime.h>
#include <cstdint>

// GRU persistent kernel v15: T=512, B=64, I=512, H=1024, O=512, fp32.
// v9 structure (256 blk x 512 thr, 128 VGPR, 96 KB swizzled weights, xT
// transposed x, sc0/sc1 coherent h/s, relaxed 2-group barrier) with A2
// ELIMINATED: z and y are block-local, so P1 computes r+z+y in ONE h pass
// (80 accumulators, chunked ldc4 -> ~115 live floats, fits 128 VGPR).
// hloc: the 8 threads whose k-slice covers the block's own j-rows copy
// h[j0..j0+7][*] to LDS during P1 -> no serialized ldc1 round trips.
// Ping-pong h buffers. Barrier A hidden by XPRE(r,z); B by XPRE(h).
// Per step:
//   P1: r,z,y_{t-1} from one h pass; s=r*hloc        -> arrive(A)
//   [XPRE r,z for t+1]                                -> wait(A)
//   P2: ht = tanh(s@W_hh + xh_pre + b_h); h' = hloc + z*(ht-hloc) -> arrive(B)
//   [XPRE h for t+1]                                  -> wait(B)

#define TT 512
#define BB 64
#define II 512
#define HH 1024
#define OO 512
#define NTHR 512

typedef float4 f4;
__device__ __forceinline__ f4 ld4(const float* p){ return *reinterpret_cast<const f4*>(p); }
// k-swizzle for ksec-stride-16 LDS weight reads (v3/v9-verified: conflicts ~0)
__device__ __forceinline__ int swz(int k){ return k ^ (((k >> 4) & 7) << 2); }

// ---- coherent (L2-bypass, L3-served) access helpers for h/s ----
__device__ __forceinline__ void ldc4(const float* p, f4* d){
  asm volatile(
    "global_load_dwordx4 %0, %4, off sc0 sc1\n\t"
    "global_load_dwordx4 %1, %4, off offset:256 sc0 sc1\n\t"
    "global_load_dwordx4 %2, %4, off offset:512 sc0 sc1\n\t"
    "global_load_dwordx4 %3, %4, off offset:768 sc0 sc1\n\t"
    "s_waitcnt vmcnt(0)"
    : "=&v"(d[0]),"=&v"(d[1]),"=&v"(d[2]),"=&v"(d[3])
    : "v"(p) : "memory");
}
__device__ __forceinline__ void ldc16(const float* p, f4* d){
  asm volatile(
    "global_load_dwordx4 %0,  %16, off sc0 sc1\n\t"
    "global_load_dwordx4 %1,  %16, off offset:256 sc0 sc1\n\t"
    "global_load_dwordx4 %2,  %16, off offset:512 sc0 sc1\n\t"
    "global_load_dwordx4 %3,  %16, off offset:768 sc0 sc1\n\t"
    "global_load_dwordx4 %4,  %16, off offset:1024 sc0 sc1\n\t"
    "global_load_dwordx4 %5,  %16, off offset:1280 sc0 sc1\n\t"
    "global_load_dwordx4 %6,  %16, off offset:1536 sc0 sc1\n\t"
    "global_load_dwordx4 %7,  %16, off offset:1792 sc0 sc1\n\t"
    "global_load_dwordx4 %8,  %16, off offset:2048 sc0 sc1\n\t"
    "global_load_dwordx4 %9,  %16, off offset:2304 sc0 sc1\n\t"
    "global_load_dwordx4 %10, %16, off offset:2560 sc0 sc1\n\t"
    "global_load_dwordx4 %11, %16, off offset:2816 sc0 sc1\n\t"
    "global_load_dwordx4 %12, %16, off offset:3072 sc0 sc1\n\t"
    "global_load_dwordx4 %13, %16, off offset:3328 sc0 sc1\n\t"
    "global_load_dwordx4 %14, %16, off offset:3584 sc0 sc1\n\t"
    "s_waitcnt vmcnt(1)\n\t"
    "global_load_dwordx4 %15, %16, off offset:3840 sc0 sc1\n\t"
    "s_waitcnt vmcnt(0)"
    : "=&v"(d[0]),"=&v"(d[1]),"=&v"(d[2]),"=&v"(d[3]),
      "=&v"(d[4]),"=&v"(d[5]),"=&v"(d[6]),"=&v"(d[7]),
      "=&v"(d[8]),"=&v"(d[9]),"=&v"(d[10]),"=&v"(d[11]),
      "=&v"(d[12]),"=&v"(d[13]),"=&v"(d[14]),"=&v"(d[15])
    : "v"(p) : "memory");
}
__device__ __forceinline__ void stc1(float* p, float v){
  asm volatile("global_store_dword %0, %1, off sc0 sc1" :: "v"(p), "v"(v) : "memory");
}

// ---------------- one-time prep kernels ----------------
__global__ void k_transpose_x(const float* __restrict__ x, float* __restrict__ xT){
  size_t total = (size_t)TT * II * BB;
  for (size_t n = (size_t)blockIdx.x * blockDim.x + threadIdx.x; n < total;
       n += (size_t)gridDim.x * blockDim.x){
    size_t t = n / ((size_t)II * BB);
    size_t rem = n % ((size_t)II * BB);
    size_t i = rem / BB, b = rem % BB;
    xT[n] = x[(t * BB + b) * II + i];
  }
}

__global__ void k_transpose_wx(const float* __restrict__ W, float* __restrict__ WT){
  size_t n = (size_t)blockIdx.x * blockDim.x + threadIdx.x;
  if (n >= (size_t)II * HH) return;
  size_t j = n / II, k = n % II;
  WT[n] = W[k * HH + j];
}

__global__ void k_transpose_h0(const float* __restrict__ st, float* __restrict__ h0){
  size_t n = (size_t)blockIdx.x * blockDim.x + threadIdx.x;
  if (n >= (size_t)HH * BB) return;
  size_t j = n / BB, b = n % BB;
  h0[n] = st[b * HH + j];
}

__global__ void k_init_bars(unsigned* bars){
  if (threadIdx.x < 512) bars[threadIdx.x] = 0;
}

// ------- barrier: per b-half group of 128 blocks; RELAXED atomics only -------
__device__ __forceinline__ void g_arrive(unsigned* bars, int g, int jt, unsigned ep){
  asm volatile("s_waitcnt vmcnt(0)" ::: "memory");
  unsigned* leaf = bars + (g * 9 + (jt & 7)) * 16;
  unsigned old = __hip_atomic_fetch_add(leaf, 1u, __ATOMIC_RELAXED, __HIP_MEMORY_SCOPE_AGENT);
  if (old + 1u == ep * 16u)
    __hip_atomic_fetch_add(bars + (g * 9 + 8) * 16, 1u, __ATOMIC_RELAXED, __HIP_MEMORY_SCOPE_AGENT);
}
__device__ __forceinline__ void g_wait(unsigned* bars, int g, unsigned ep){
  unsigned* root = bars + (g * 9 + 8) * 16;
  while (__hip_atomic_load(root, __ATOMIC_RELAXED, __HIP_MEMORY_SCOPE_AGENT) < ep * 8u)
    __builtin_amdgcn_s_sleep(1);
}

// shfl-reduce over the 3 ksec bits inside a wave (lanes 8,16,32)
#define WREDUCE(v) { v += __shfl_xor(v, 8); v += __shfl_xor(v, 16); v += __shfl_xor(v, 32); }

// ---------------- the persistent GRU kernel ----------------
__global__ __launch_bounds__(NTHR, 2) void k_gru(
    const float* __restrict__ xT,
    const float* __restrict__ WxTr, const float* __restrict__ WxTz, const float* __restrict__ WxTh,
    float* __restrict__ hb0, float* __restrict__ hb1, float* __restrict__ s,
    const float* __restrict__ W_zh, const float* __restrict__ b_z,
    const float* __restrict__ W_rh, const float* __restrict__ b_r,
    const float* __restrict__ W_hh, const float* __restrict__ b_h,
    const float* __restrict__ W_out, const float* __restrict__ b_out,
    float* __restrict__ out, unsigned* __restrict__ bars)
{
  __shared__ float sW[3 * 8 * 1024];   // [0=RH,1=ZH,2=HH][c<8][k swz]  96 KB
  __shared__ float red[8 * 656];       // cross-wave reduce             21 KB
  __shared__ float xpre[3][256];       // x-projections (8c x 32b)
  __shared__ float sZ[256];            // z gate
  __shared__ float hloc[16][32];       // block's own h rows (j0..j0+7 at off j0&15)
  __shared__ float sBias[32];          // b_r[8] b_z[8] b_h[8] b_out[4]

  const int tid = threadIdx.x;
  const int bid = blockIdx.x;
  const int jt = bid & 127, bhalf = bid >> 7;
  const int j0 = jt * 8, o0 = jt * 4, bbase = bhalf * 32;
  const int jrow = j0 & 15;            // row offset of j0 within its 16-row slice

  // ---- prologue: weight slices -> swizzled LDS ----
  #pragma unroll
  for (int kk2 = 0; kk2 < 2; ++kk2){
    const int k = tid * 2 + kk2;           // 0..1023
    f4 vr  = ld4(W_rh + (size_t)k * HH + j0);
    f4 vr2 = ld4(W_rh + (size_t)k * HH + j0 + 4);
    f4 vz  = ld4(W_zh + (size_t)k * HH + j0);
    f4 vz2 = ld4(W_zh + (size_t)k * HH + j0 + 4);
    f4 vh  = ld4(W_hh + (size_t)k * HH + j0);
    f4 vh2 = ld4(W_hh + (size_t)k * HH + j0 + 4);
    const int kx = swz(k);
    float ar[8] = {vr.x,vr.y,vr.z,vr.w,vr2.x,vr2.y,vr2.z,vr2.w};
    float az[8] = {vz.x,vz.y,vz.z,vz.w,vz2.x,vz2.y,vz2.z,vz2.w};
    float ah[8] = {vh.x,vh.y,vh.z,vh.w,vh2.x,vh2.y,vh2.z,vh2.w};
    #pragma unroll
    for (int c = 0; c < 8; ++c){
      sW[0*8192 + c*1024 + kx] = ar[c];
      sW[1*8192 + c*1024 + kx] = az[c];
      sW[2*8192 + c*1024 + kx] = ah[c];
    }
  }
  if (tid < 8){
    sBias[tid]      = b_r[j0 + tid];
    sBias[8 + tid]  = b_z[j0 + tid];
    sBias[16 + tid] = b_h[j0 + tid];
    if (tid < 4) sBias[24 + tid] = b_out[o0 + tid];
  }

  const int bg = tid & 7, b0 = bbase + bg * 4;
  const int ksec = tid >> 3;           // 0..63
  const int wv = tid >> 6;             // wave 0..7
  const bool wr0 = ((tid & 56) == 0);
  const int kh0 = ksec * 16;           // K=1024 / 64
  const int kx0 = ksec * 8;            // K=512  / 64
  const bool own = (ksec == (jt >> 1));  // this thread's k-slice holds rows j0..j0+7
  __syncthreads();

  // ---- XPRE macros: x-projections for step tc (v9 coalesced layout) ----
  #define XPRE01(tc_) do {                                                   \
    float aXr_[8][4] = {}, aXz_[8][4] = {};                                  \
    const float* xb_ = xT + (size_t)(tc_) * II * BB + kx0 * BB + b0;         \
    _Pragma("unroll")                                                        \
    for (int i4 = 0; i4 < 2; ++i4){                                          \
      f4 xv4_[4];                                                            \
      _Pragma("unroll")                                                      \
      for (int kk = 0; kk < 4; ++kk) xv4_[kk] = ld4(xb_ + (i4*4+kk) * BB);   \
      _Pragma("unroll")                                                      \
      for (int c = 0; c < 8; ++c){                                           \
        f4 wr_ = ld4(WxTr + (size_t)(j0 + c) * II + kx0 + i4*4);             \
        f4 wz_ = ld4(WxTz + (size_t)(j0 + c) * II + kx0 + i4*4);             \
        float wrv_[4] = {wr_.x, wr_.y, wr_.z, wr_.w};                        \
        float wzv_[4] = {wz_.x, wz_.y, wz_.z, wz_.w};                        \
        _Pragma("unroll")                                                    \
        for (int kk = 0; kk < 4; ++kk){                                      \
          const f4 xv_ = xv4_[kk];                                           \
          aXr_[c][0] = fmaf(wrv_[kk], xv_.x, aXr_[c][0]);                    \
          aXr_[c][1] = fmaf(wrv_[kk], xv_.y, aXr_[c][1]);                    \
          aXr_[c][2] = fmaf(wrv_[kk], xv_.z, aXr_[c][2]);                    \
          aXr_[c][3] = fmaf(wrv_[kk], xv_.w, aXr_[c][3]);                    \
          aXz_[c][0] = fmaf(wzv_[kk], xv_.x, aXz_[c][0]);                    \
          aXz_[c][1] = fmaf(wzv_[kk], xv_.y, aXz_[c][1]);                    \
          aXz_[c][2] = fmaf(wzv_[kk], xv_.z, aXz_[c][2]);                    \
          aXz_[c][3] = fmaf(wzv_[kk], xv_.w, aXz_[c][3]);                    \
        }                                                                    \
      }                                                                      \
    }                                                                        \
    _Pragma("unroll")                                                        \
    for (int c = 0; c < 8; ++c)                                              \
      _Pragma("unroll")                                                      \
      for (int bb = 0; bb < 4; ++bb){ WREDUCE(aXr_[c][bb]); WREDUCE(aXz_[c][bb]); } \
    if (wr0)                                                                 \
      _Pragma("unroll")                                                      \
      for (int c = 0; c < 8; ++c)                                            \
        _Pragma("unroll")                                                    \
        for (int bb = 0; bb < 4; ++bb){                                      \
          red[wv*656 + c*32 + bg*4 + bb]       = aXr_[c][bb];                \
          red[wv*656 + 256 + c*32 + bg*4 + bb] = aXz_[c][bb];                \
        }                                                                    \
    __syncthreads();                                                         \
    {                                                                        \
      float sum_ = 0.f;                                                      \
      _Pragma("unroll")                                                      \
      for (int w = 0; w < 8; ++w) sum_ += red[w*656 + tid];                  \
      if (tid < 256) xpre[0][tid] = sum_;                                    \
      else           xpre[1][tid - 256] = sum_;                              \
    }                                                                        \
    __syncthreads();                                                         \
  } while (0)

  #define XPRE2(tc_) do {                                                    \
    float aXh_[8][4] = {};                                                   \
    const float* xb_ = xT + (size_t)(tc_) * II * BB + kx0 * BB + b0;         \
    _Pragma("unroll")                                                        \
    for (int i4 = 0; i4 < 2; ++i4){                                          \
      f4 xv4_[4];                                                            \
      _Pragma("unroll")                                                      \
      for (int kk = 0; kk < 4; ++kk) xv4_[kk] = ld4(xb_ + (i4*4+kk) * BB);   \
      _Pragma("unroll")                                                      \
      for (int c = 0; c < 8; ++c){                                           \
        f4 wh_ = ld4(WxTh + (size_t)(j0 + c) * II + kx0 + i4*4);             \
        float whv_[4] = {wh_.x, wh_.y, wh_.z, wh_.w};                        \
        _Pragma("unroll")                                                    \
        for (int kk = 0; kk < 4; ++kk){                                      \
          const f4 xv_ = xv4_[kk];                                           \
          aXh_[c][0] = fmaf(whv_[kk], xv_.x, aXh_[c][0]);                    \
          aXh_[c][1] = fmaf(whv_[kk], xv_.y, aXh_[c][1]);                    \
          aXh_[c][2] = fmaf(whv_[kk], xv_.z, aXh_[c][2]);                    \
          aXh_[c][3] = fmaf(whv_[kk], xv_.w, aXh_[c][3]);                    \
        }                                                                    \
      }                                                                      \
    }                                                                        \
    _Pragma("unroll")                                                        \
    for (int c = 0; c < 8; ++c)                                              \
      _Pragma("unroll")                                                      \
      for (int bb = 0; bb < 4; ++bb) WREDUCE(aXh_[c][bb]);                   \
    if (wr0)                                                                 \
      _Pragma("unroll")                                                      \
      for (int c = 0; c < 8; ++c)                                            \
        _Pragma("unroll")                                                    \
        for (int bb = 0; bb < 4; ++bb)                                       \
          red[wv*656 + c*32 + bg*4 + bb] = aXh_[c][bb];                      \
    __syncthreads();                                                         \
    if (tid < 256){                                                          \
      float sum_ = 0.f;                                                      \
      _Pragma("unroll")                                                      \
      for (int w = 0; w < 8; ++w) sum_ += red[w*656 + tid];                  \
      xpre[2][tid] = sum_;                                                   \
    }                                                                        \
    __syncthreads();                                                         \
  } while (0)

  for (int t = -1; t < TT; ++t){
    if (t < 0){ XPRE01(0); XPRE2(0); continue; }
    const float* hin  = (t & 1) ? hb1 : hb0;
    float*       hout = (t & 1) ? hb0 : hb1;

    // ===== P1: r + z + y_{t-1} from ONE coherent h pass; hloc capture =====
    {
      float aR[8][4] = {}, aZ[8][4] = {}, aY[4][4] = {};
      const float* hb = hin + kh0 * BB + b0;
      #pragma unroll
      for (int i4 = 0; i4 < 4; ++i4){
        f4 hv4[4];
        ldc4(hb + i4*4*BB, hv4);
        if (own){
          #pragma unroll
          for (int kk = 0; kk < 4; ++kk)
            *reinterpret_cast<f4*>(&hloc[i4*4+kk][bg*4]) = hv4[kk];
        }
        const int kc = kh0 + i4*4;
        const int kxc = swz(kc);
        #pragma unroll
        for (int c = 0; c < 8; ++c){
          f4 wr_ = *reinterpret_cast<const f4*>(&sW[0*8192 + c*1024 + kxc]);
          f4 wz_ = *reinterpret_cast<const f4*>(&sW[1*8192 + c*1024 + kxc]);
          float wrv[4] = {wr_.x, wr_.y, wr_.z, wr_.w};
          float wzv[4] = {wz_.x, wz_.y, wz_.z, wz_.w};
          #pragma unroll
          for (int kk = 0; kk < 4; ++kk){
            const f4 hv = hv4[kk];
            aR[c][0] = fmaf(wrv[kk], hv.x, aR[c][0]);
            aR[c][1] = fmaf(wrv[kk], hv.y, aR[c][1]);
            aR[c][2] = fmaf(wrv[kk], hv.z, aR[c][2]);
            aR[c][3] = fmaf(wrv[kk], hv.w, aR[c][3]);
            aZ[c][0] = fmaf(wzv[kk], hv.x, aZ[c][0]);
            aZ[c][1] = fmaf(wzv[kk], hv.y, aZ[c][1]);
            aZ[c][2] = fmaf(wzv[kk], hv.z, aZ[c][2]);
            aZ[c][3] = fmaf(wzv[kk], hv.w, aZ[c][3]);
          }
        }
        #pragma unroll
        for (int oc = 0; oc < 4; ++oc){
          f4 wo = ld4(W_out + (size_t)(o0 + oc) * HH + kc);   // L2-hot
          float wvv[4] = {wo.x, wo.y, wo.z, wo.w};
          #pragma unroll
          for (int kk = 0; kk < 4; ++kk){
            const f4 hv = hv4[kk];
            aY[oc][0] = fmaf(wvv[kk], hv.x, aY[oc][0]);
            aY[oc][1] = fmaf(wvv[kk], hv.y, aY[oc][1]);
            aY[oc][2] = fmaf(wvv[kk], hv.z, aY[oc][2]);
            aY[oc][3] = fmaf(wvv[kk], hv.w, aY[oc][3]);
          }
        }
      }
      #pragma unroll
      for (int c = 0; c < 8; ++c)
        #pragma unroll
        for (int bb = 0; bb < 4; ++bb){ WREDUCE(aR[c][bb]); WREDUCE(aZ[c][bb]); }
      #pragma unroll
      for (int oc = 0; oc < 4; ++oc)
        #pragma unroll
        for (int bb = 0; bb < 4; ++bb) WREDUCE(aY[oc][bb]);
      if (wr0){
        #pragma unroll
        for (int c = 0; c < 8; ++c)
          #pragma unroll
          for (int bb = 0; bb < 4; ++bb){
            red[wv*656 + c*32 + bg*4 + bb]       = aR[c][bb];
            red[wv*656 + 256 + c*32 + bg*4 + bb] = aZ[c][bb];
          }
        #pragma unroll
        for (int oc = 0; oc < 4; ++oc)
          #pragma unroll
          for (int bb = 0; bb < 4; ++bb)
            red[wv*656 + 512 + oc*32 + bg*4 + bb] = aY[oc][bb];
      }
    }
    __syncthreads();
    if (tid < 256){
      float sumR = 0.f, sumZ = 0.f;
      #pragma unroll
      for (int w = 0; w < 8; ++w){
        sumR += red[w*656 + tid];
        sumZ += red[w*656 + 256 + tid];
      }
      const int c = tid >> 5, bl = tid & 31;
      const float rr = 1.f / (1.f + expf(-(sumR + xpre[0][tid] + sBias[c])));
      sZ[tid] = 1.f / (1.f + expf(-(sumZ + xpre[1][tid] + sBias[8 + c])));
      stc1(&s[(j0 + c)*BB + bbase + bl], rr * hloc[jrow + c][bl]);
    } else if (tid < 384){
      const int idx = tid - 256;
      float sumY = 0.f;
      #pragma unroll
      for (int w = 0; w < 8; ++w) sumY += red[w*656 + 512 + idx];
      const int oc = idx >> 5, bl = idx & 31;
      if (t > 0)
        out[((size_t)(t-1)*BB + bbase + bl)*OO + o0 + oc] = sumY + sBias[24 + oc];
    }
    __syncthreads();                       // drains s stores per-wave
    if (tid == 0) g_arrive(bars, bhalf, jt, 2*t + 1);

    // ===== shadow-A: xpre r,z for t+1 (hides barrier A) =====
    if (t + 1 < TT) XPRE01(t + 1);
    if (tid == 0) g_wait(bars, bhalf, 2*t + 1);
    __syncthreads();

    // ===== P2: candidate + h update =====
    {
      float aH[8][4] = {};
      f4 sv16[16];
      ldc16(s + kh0 * BB + b0, sv16);      // coherent s read
      #pragma unroll
      for (int i4 = 0; i4 < 4; ++i4){
        const int kxc = swz(kh0 + i4*4);
        #pragma unroll
        for (int c = 0; c < 8; ++c){
          f4 wf = *reinterpret_cast<const f4*>(&sW[2*8192 + c*1024 + kxc]);
          float wvv[4] = {wf.x, wf.y, wf.z, wf.w};
          #pragma unroll
          for (int kk = 0; kk < 4; ++kk){
            const f4 sv = sv16[i4*4+kk];
            aH[c][0] = fmaf(wvv[kk], sv.x, aH[c][0]);
            aH[c][1] = fmaf(wvv[kk], sv.y, aH[c][1]);
            aH[c][2] = fmaf(wvv[kk], sv.z, aH[c][2]);
            aH[c][3] = fmaf(wvv[kk], sv.w, aH[c][3]);
          }
        }
      }
      #pragma unroll
      for (int c = 0; c < 8; ++c)
        #pragma unroll
        for (int bb = 0; bb < 4; ++bb) WREDUCE(aH[c][bb]);
      if (wr0)
        #pragma unroll
        for (int c = 0; c < 8; ++c)
          #pragma unroll
          for (int bb = 0; bb < 4; ++bb)
            red[wv*656 + c*32 + bg*4 + bb] = aH[c][bb];
    }
    __syncthreads();
    if (tid < 256){
      float sum = 0.f;
      #pragma unroll
      for (int w = 0; w < 8; ++w) sum += red[w*656 + tid];
      const int c = tid >> 5, bl = tid & 31;
      const float ht = tanhf(sum + xpre[2][tid] + sBias[16 + c]);
      const float z = sZ[tid];
      const float hold = hloc[jrow + c][bl];
      const float hnew = fmaf(z, ht - hold, hold);
      stc1(&hout[(j0 + c)*BB + bbase + bl], hnew);
      if (t == TT - 1) out[(size_t)TT*BB*OO + (size_t)(bbase + bl)*HH + j0 + c] = hnew;
    }
    __syncthreads();                       // drains h stores per-wave
    if (tid == 0) g_arrive(bars, bhalf, jt, 2*t + 2);

    // ===== shadow-B: xpre h for t+1 (hides barrier B) =====
    if (t + 1 < TT) XPRE2(t + 1);
    if (tid == 0) g_wait(bars, bhalf, 2*t + 2);
    __syncthreads();
  }

  // ================= trailing y_{TT-1} from final h (TT even -> hb0) ====
  {
    const float* hfin = (TT & 1) ? hb1 : hb0;
    float aY[4][4] = {};
    f4 hv16[16];
    ldc16(hfin + kh0 * BB + b0, hv16);
    #pragma unroll
    for (int i4 = 0; i4 < 4; ++i4){
      const int kc = kh0 + i4*4;
      #pragma unroll
      for (int oc = 0; oc < 4; ++oc){
        f4 wo = ld4(W_out + (size_t)(o0 + oc) * HH + kc);
        float wvv[4] = {wo.x, wo.y, wo.z, wo.w};
        #pragma unroll
        for (int kk = 0; kk < 4; ++kk){
          const f4 hv = hv16[i4*4+kk];
          aY[oc][0] = fmaf(wvv[kk], hv.x, aY[oc][0]);
          aY[oc][1] = fmaf(wvv[kk], hv.y, aY[oc][1]);
          aY[oc][2] = fmaf(wvv[kk], hv.z, aY[oc][2]);
          aY[oc][3] = fmaf(wvv[kk], hv.w, aY[oc][3]);
        }
      }
    }
    #pragma unroll
    for (int oc = 0; oc < 4; ++oc)
      #pragma unroll
      for (int bb = 0; bb < 4; ++bb) WREDUCE(aY[oc][bb]);
    if (wr0)
      #pragma unroll
      for (int oc = 0; oc < 4; ++oc)
        #pragma unroll
        for (int bb = 0; bb < 4; ++bb)
          red[wv*656 + oc*32 + bg*4 + bb] = aY[oc][bb];
    __syncthreads();
    if (tid < 128){
      float sum = 0.f;
      #pragma unroll
      for (int w = 0; w < 8; ++w) sum += red[w*656 + tid];
      const int oc = tid >> 5, bl = tid & 31;
      out[((size_t)(TT-1)*BB + bbase + bl)*OO + o0 + oc] = sum + sBias[24 + oc];
    }
  }
  #undef XPRE01
  #undef XPRE2
}

// ---------------- host ----------------
extern "C" void kernel_launch(void* const* d_in, const int* in_sizes, int n_in,
                              void* d_out, int out_size, void* d_ws, size_t ws_size,
                              hipStream_t stream) {
  const float* x     = (const float*)d_in[0];
  const float* st    = (const float*)d_in[1];
  const float* W_zh  = (const float*)d_in[2];
  const float* W_zx  = (const float*)d_in[3];
  const float* b_z   = (const float*)d_in[4];
  const float* W_rh  = (const float*)d_in[5];
  const float* W_rx  = (const float*)d_in[6];
  const float* b_r   = (const float*)d_in[7];
  const float* W_hh  = (const float*)d_in[8];
  const float* W_hx  = (const float*)d_in[9];
  const float* b_h   = (const float*)d_in[10];
  const float* W_out = (const float*)d_in[11];
  const float* b_out = (const float*)d_in[12];
  float* out = (float*)d_out;
  float* ws  = (float*)d_ws;

  const size_t xT_sz = (size_t)TT * II * BB;   // 16,777,216
  const size_t wx_sz = (size_t)II * HH;        //    524,288
  const size_t h_sz  = (size_t)HH * BB;        //     65,536
  const size_t need  = (xT_sz + 3*wx_sz + 3*h_sz) * sizeof(float) + 512*sizeof(unsigned);
  if (ws_size < need) return;

  float* xT   = ws;
  float* WxTr = xT + xT_sz;
  float* WxTz = WxTr + wx_sz;
  float* WxTh = WxTz + wx_sz;
  float* hb0  = WxTh + wx_sz;
  float* hb1  = hb0 + h_sz;
  float* s    = hb1 + h_sz;
  unsigned* bars = (unsigned*)(s + h_sz);

  k_transpose_x <<<8192, 256, 0, stream>>>(x, xT);
  k_transpose_wx<<<2048, 256, 0, stream>>>(W_rx, WxTr);
  k_transpose_wx<<<2048, 256, 0, stream>>>(W_zx, WxTz);
  k_transpose_wx<<<2048, 256, 0, stream>>>(W_hx, WxTh);
  k_transpose_h0<<< 256, 256, 0, stream>>>(st, hb0);
  k_init_bars   <<<   1, 512, 0, stream>>>(bars);

  k_gru<<<256, NTHR, 0, stream>>>(xT, WxTr, WxTz, WxTh, hb0, hb1, s,
                                  W_zh, b_z, W_rh, b_r, W_hh, b_h,
                                  W_out, b_out, out, bars);
}

// Round 18
// 12978.777 us; speedup vs baseline: 2.5447x; 1.8518x over previous
//
#include <hip/hip_runtime.h>
#include <cstdint>

// GRU persistent kernel v16: T=512, B=64, I=512, H=1024, O=512, fp32.
// == v9 (best: 13.6 ms k_gru) + hloc: the 8 threads whose k-slice covers the
// block's own j-rows copy h[j0..j0+7 within slice][*] to LDS during P1's
// stash load -> the two serialized sc0/sc1 ldc1 L3 round-trips per step
// (P1 epilogue s=r*h re-read, P2 epilogue hold re-read) disappear.
// Everything else identical to v9: 256 blk x 512 thr, 128 VGPR, 96 KB
// swizzled weights, xT-transposed x, sc0/sc1 coherent h/s, relaxed 2-group
// barrier. Phases per step:
//   P1: r = sigmoid(h@W_rh + xr_pre + b_r); s = r*hloc; stash h -> arrive(A)
//   A2: z = sigmoid(h@W_zh + xz_pre + b_z); y_{t-1}=h@Wout (stash) -> wait(A)
//   P2: ht = tanh(s@W_hh + xh_pre + b_h); h' = hloc + z*(ht-hloc) -> arrive(B)
//   C : xr/xz/xh_pre for t+1 (hides barrier B)                    -> wait(B)

#define TT 512
#define BB 64
#define II 512
#define HH 1024
#define OO 512
#define NTHR 512

typedef float4 f4;
__device__ __forceinline__ f4 ld4(const float* p){ return *reinterpret_cast<const f4*>(p); }
// k-swizzle for ksec-stride-16 LDS weight reads (v3/v9-verified: conflicts ~0)
__device__ __forceinline__ int swz(int k){ return k ^ (((k >> 4) & 7) << 2); }

// ---- coherent (L2-bypass, L3-served) access helpers for h/s ----
__device__ __forceinline__ void ldc16(const float* p, f4* d){
  asm volatile(
    "global_load_dwordx4 %0,  %16, off sc0 sc1\n\t"
    "global_load_dwordx4 %1,  %16, off offset:256 sc0 sc1\n\t"
    "global_load_dwordx4 %2,  %16, off offset:512 sc0 sc1\n\t"
    "global_load_dwordx4 %3,  %16, off offset:768 sc0 sc1\n\t"
    "global_load_dwordx4 %4,  %16, off offset:1024 sc0 sc1\n\t"
    "global_load_dwordx4 %5,  %16, off offset:1280 sc0 sc1\n\t"
    "global_load_dwordx4 %6,  %16, off offset:1536 sc0 sc1\n\t"
    "global_load_dwordx4 %7,  %16, off offset:1792 sc0 sc1\n\t"
    "global_load_dwordx4 %8,  %16, off offset:2048 sc0 sc1\n\t"
    "global_load_dwordx4 %9,  %16, off offset:2304 sc0 sc1\n\t"
    "global_load_dwordx4 %10, %16, off offset:2560 sc0 sc1\n\t"
    "global_load_dwordx4 %11, %16, off offset:2816 sc0 sc1\n\t"
    "global_load_dwordx4 %12, %16, off offset:3072 sc0 sc1\n\t"
    "global_load_dwordx4 %13, %16, off offset:3328 sc0 sc1\n\t"
    "global_load_dwordx4 %14, %16, off offset:3584 sc0 sc1\n\t"
    "s_waitcnt vmcnt(1)\n\t"
    "global_load_dwordx4 %15, %16, off offset:3840 sc0 sc1\n\t"
    "s_waitcnt vmcnt(0)"
    : "=&v"(d[0]),"=&v"(d[1]),"=&v"(d[2]),"=&v"(d[3]),
      "=&v"(d[4]),"=&v"(d[5]),"=&v"(d[6]),"=&v"(d[7]),
      "=&v"(d[8]),"=&v"(d[9]),"=&v"(d[10]),"=&v"(d[11]),
      "=&v"(d[12]),"=&v"(d[13]),"=&v"(d[14]),"=&v"(d[15])
    : "v"(p) : "memory");
}
__device__ __forceinline__ void stc1(float* p, float v){
  asm volatile("global_store_dword %0, %1, off sc0 sc1" :: "v"(p), "v"(v) : "memory");
}

// ---------------- one-time prep kernels ----------------
__global__ void k_transpose_x(const float* __restrict__ x, float* __restrict__ xT){
  size_t total = (size_t)TT * II * BB;
  for (size_t n = (size_t)blockIdx.x * blockDim.x + threadIdx.x; n < total;
       n += (size_t)gridDim.x * blockDim.x){
    size_t t = n / ((size_t)II * BB);
    size_t rem = n % ((size_t)II * BB);
    size_t i = rem / BB, b = rem % BB;
    xT[n] = x[(t * BB + b) * II + i];
  }
}

__global__ void k_transpose_wx(const float* __restrict__ W, float* __restrict__ WT){
  size_t n = (size_t)blockIdx.x * blockDim.x + threadIdx.x;
  if (n >= (size_t)II * HH) return;
  size_t j = n / II, k = n % II;
  WT[n] = W[k * HH + j];
}

__global__ void k_transpose_h0(const float* __restrict__ st, float* __restrict__ h0){
  size_t n = (size_t)blockIdx.x * blockDim.x + threadIdx.x;
  if (n >= (size_t)HH * BB) return;
  size_t j = n / BB, b = n % BB;
  h0[n] = st[b * HH + j];
}

__global__ void k_init_bars(unsigned* bars){
  if (threadIdx.x < 512) bars[threadIdx.x] = 0;
}

// ------- barrier: per b-half group of 128 blocks; RELAXED atomics only -------
__device__ __forceinline__ void g_arrive(unsigned* bars, int g, int jt, unsigned ep){
  asm volatile("s_waitcnt vmcnt(0)" ::: "memory");   // drain sc1 data stores
  unsigned* leaf = bars + (g * 9 + (jt & 7)) * 16;
  unsigned old = __hip_atomic_fetch_add(leaf, 1u, __ATOMIC_RELAXED, __HIP_MEMORY_SCOPE_AGENT);
  if (old + 1u == ep * 16u)
    __hip_atomic_fetch_add(bars + (g * 9 + 8) * 16, 1u, __ATOMIC_RELAXED, __HIP_MEMORY_SCOPE_AGENT);
}
__device__ __forceinline__ void g_wait(unsigned* bars, int g, unsigned ep){
  unsigned* root = bars + (g * 9 + 8) * 16;
  while (__hip_atomic_load(root, __ATOMIC_RELAXED, __HIP_MEMORY_SCOPE_AGENT) < ep * 8u)
    __builtin_amdgcn_s_sleep(1);
}

// shfl-reduce over the 3 ksec bits inside a wave (lanes 8,16,32)
#define WREDUCE(v) { v += __shfl_xor(v, 8); v += __shfl_xor(v, 16); v += __shfl_xor(v, 32); }

// ---------------- the persistent GRU kernel ----------------
__global__ __launch_bounds__(NTHR, 2) void k_gru(
    const float* __restrict__ xT,
    const float* __restrict__ WxTr, const float* __restrict__ WxTz, const float* __restrict__ WxTh,
    float* __restrict__ h, float* __restrict__ s,
    const float* __restrict__ W_zh, const float* __restrict__ b_z,
    const float* __restrict__ W_rh, const float* __restrict__ b_r,
    const float* __restrict__ W_hh, const float* __restrict__ b_h,
    const float* __restrict__ W_out, const float* __restrict__ b_out,
    float* __restrict__ out, unsigned* __restrict__ bars)
{
  __shared__ float sW[3 * 8 * 1024];   // [0=RH,1=ZH,2=HH][c<8][k swz]  96 KB
  __shared__ float red[8 * 528];       // cross-wave reduce             16.9 KB
  __shared__ float xpre[3][256];       // x-projections (8c x 32b)
  __shared__ float sZ[256];            // z gate
  __shared__ float hloc[16][32];       // block's own h slice (2 KB)
  __shared__ float sBias[32];          // b_r[8] b_z[8] b_h[8] b_out[4]

  const int tid = threadIdx.x;
  const int bid = blockIdx.x;
  const int jt = bid & 127, bhalf = bid >> 7;
  const int j0 = jt * 8, o0 = jt * 4, bbase = bhalf * 32;
  const int jrow = (jt & 1) * 8;       // offset of j0 within its 16-row k-slice

  // ---- prologue: weight slices -> swizzled LDS ----
  #pragma unroll
  for (int kk2 = 0; kk2 < 2; ++kk2){
    const int k = tid * 2 + kk2;           // 0..1023
    f4 vr  = ld4(W_rh + (size_t)k * HH + j0);
    f4 vr2 = ld4(W_rh + (size_t)k * HH + j0 + 4);
    f4 vz  = ld4(W_zh + (size_t)k * HH + j0);
    f4 vz2 = ld4(W_zh + (size_t)k * HH + j0 + 4);
    f4 vh  = ld4(W_hh + (size_t)k * HH + j0);
    f4 vh2 = ld4(W_hh + (size_t)k * HH + j0 + 4);
    const int kx = swz(k);
    float ar[8] = {vr.x,vr.y,vr.z,vr.w,vr2.x,vr2.y,vr2.z,vr2.w};
    float az[8] = {vz.x,vz.y,vz.z,vz.w,vz2.x,vz2.y,vz2.z,vz2.w};
    float ah[8] = {vh.x,vh.y,vh.z,vh.w,vh2.x,vh2.y,vh2.z,vh2.w};
    #pragma unroll
    for (int c = 0; c < 8; ++c){
      sW[0*8192 + c*1024 + kx] = ar[c];
      sW[1*8192 + c*1024 + kx] = az[c];
      sW[2*8192 + c*1024 + kx] = ah[c];
    }
  }
  if (tid < 8){
    sBias[tid]      = b_r[j0 + tid];
    sBias[8 + tid]  = b_z[j0 + tid];
    sBias[16 + tid] = b_h[j0 + tid];
    if (tid < 4) sBias[24 + tid] = b_out[o0 + tid];
  }

  const int bg = tid & 7, b0 = bbase + bg * 4;
  const int ksec = tid >> 3;           // 0..63
  const int wv = tid >> 6;             // wave 0..7
  const bool wr0 = ((tid & 56) == 0);
  const int kh0 = ksec * 16;           // K=1024 / 64
  const int kx0 = ksec * 8;            // K=512  / 64
  const bool own = (ksec == (jt >> 1));  // this k-slice holds rows j0..j0+7
  __syncthreads();

  for (int t = -1; t < TT; ++t){
    f4 st4[16];                        // h stash, P1 -> A2
    if (t >= 0){
      // ================= P1: r gate (+hloc capture) =================
      float aR[8][4] = {};
      ldc16(h + kh0 * BB + b0, st4);   // coherent h read (16 k x 4 b)
      if (own){
        #pragma unroll
        for (int kk = 0; kk < 16; ++kk)
          *reinterpret_cast<f4*>(&hloc[kk][bg*4]) = st4[kk];
      }
      #pragma unroll
      for (int i4 = 0; i4 < 4; ++i4){
        const int kxc = swz(kh0 + i4*4);
        #pragma unroll
        for (int c = 0; c < 8; ++c){
          f4 wf = *reinterpret_cast<const f4*>(&sW[0*8192 + c*1024 + kxc]);
          float wvv[4] = {wf.x, wf.y, wf.z, wf.w};
          #pragma unroll
          for (int kk = 0; kk < 4; ++kk){
            const f4 hv = st4[i4*4+kk];
            aR[c][0] = fmaf(wvv[kk], hv.x, aR[c][0]);
            aR[c][1] = fmaf(wvv[kk], hv.y, aR[c][1]);
            aR[c][2] = fmaf(wvv[kk], hv.z, aR[c][2]);
            aR[c][3] = fmaf(wvv[kk], hv.w, aR[c][3]);
          }
        }
      }
      #pragma unroll
      for (int c = 0; c < 8; ++c)
        #pragma unroll
        for (int bb = 0; bb < 4; ++bb) WREDUCE(aR[c][bb]);
      if (wr0)
        #pragma unroll
        for (int c = 0; c < 8; ++c)
          #pragma unroll
          for (int bb = 0; bb < 4; ++bb)
            red[wv*528 + c*32 + bg*4 + bb] = aR[c][bb];
      __syncthreads();
      if (tid < 256){
        float sum = 0.f;
        #pragma unroll
        for (int w = 0; w < 8; ++w) sum += red[w*528 + tid];
        const int c = tid >> 5, bl = tid & 31;
        const float v = sum + xpre[0][tid] + sBias[c];
        const float rr = 1.f / (1.f + expf(-v));
        stc1(&s[(j0 + c)*BB + bbase + bl], rr * hloc[jrow + c][bl]);
      }
      __syncthreads();
      if (tid == 0) g_arrive(bars, bhalf, jt, 2*t + 1);

      // ========== A2: z gate + y_{t-1} from stash (hides barrier A) ==========
      float aZ[8][4] = {};
      float aY[4][4] = {};
      #pragma unroll
      for (int i4 = 0; i4 < 4; ++i4){
        const int kc = kh0 + i4*4;
        const int kxc = swz(kc);
        #pragma unroll
        for (int c = 0; c < 8; ++c){
          f4 wf = *reinterpret_cast<const f4*>(&sW[1*8192 + c*1024 + kxc]);
          float wvv[4] = {wf.x, wf.y, wf.z, wf.w};
          #pragma unroll
          for (int kk = 0; kk < 4; ++kk){
            const f4 hv = st4[i4*4+kk];
            aZ[c][0] = fmaf(wvv[kk], hv.x, aZ[c][0]);
            aZ[c][1] = fmaf(wvv[kk], hv.y, aZ[c][1]);
            aZ[c][2] = fmaf(wvv[kk], hv.z, aZ[c][2]);
            aZ[c][3] = fmaf(wvv[kk], hv.w, aZ[c][3]);
          }
        }
        #pragma unroll
        for (int oc = 0; oc < 4; ++oc){
          f4 wo = ld4(W_out + (size_t)(o0 + oc) * HH + kc);   // L2-hot
          float wvv[4] = {wo.x, wo.y, wo.z, wo.w};
          #pragma unroll
          for (int kk = 0; kk < 4; ++kk){
            const f4 hv = st4[i4*4+kk];
            aY[oc][0] = fmaf(wvv[kk], hv.x, aY[oc][0]);
            aY[oc][1] = fmaf(wvv[kk], hv.y, aY[oc][1]);
            aY[oc][2] = fmaf(wvv[kk], hv.z, aY[oc][2]);
            aY[oc][3] = fmaf(wvv[kk], hv.w, aY[oc][3]);
          }
        }
      }
      #pragma unroll
      for (int c = 0; c < 8; ++c)
        #pragma unroll
        for (int bb = 0; bb < 4; ++bb) WREDUCE(aZ[c][bb]);
      #pragma unroll
      for (int oc = 0; oc < 4; ++oc)
        #pragma unroll
        for (int bb = 0; bb < 4; ++bb) WREDUCE(aY[oc][bb]);
      if (wr0){
        #pragma unroll
        for (int c = 0; c < 8; ++c)
          #pragma unroll
          for (int bb = 0; bb < 4; ++bb)
            red[wv*528 + c*32 + bg*4 + bb] = aZ[c][bb];
        #pragma unroll
        for (int oc = 0; oc < 4; ++oc)
          #pragma unroll
          for (int bb = 0; bb < 4; ++bb)
            red[wv*528 + 256 + oc*32 + bg*4 + bb] = aY[oc][bb];
      }
      __syncthreads();
      if (tid < 256){
        float sum = 0.f;
        #pragma unroll
        for (int w = 0; w < 8; ++w) sum += red[w*528 + tid];
        const int c = tid >> 5;
        sZ[tid] = 1.f / (1.f + expf(-(sum + xpre[1][tid] + sBias[8 + c])));
      } else if (tid < 384){
        const int idx = tid - 256;
        float sum = 0.f;
        #pragma unroll
        for (int w = 0; w < 8; ++w) sum += red[w*528 + tid];
        const int oc = idx >> 5, bl = idx & 31;
        if (t > 0)
          out[((size_t)(t-1)*BB + bbase + bl)*OO + o0 + oc] = sum + sBias[24 + oc];
      }
      if (tid == 0) g_wait(bars, bhalf, 2*t + 1);
      __syncthreads();

      // ================= P2: candidate + h update =================
      float aH[8][4] = {};
      f4 sv16[16];
      ldc16(s + kh0 * BB + b0, sv16);  // coherent s read
      #pragma unroll
      for (int i4 = 0; i4 < 4; ++i4){
        const int kxc = swz(kh0 + i4*4);
        #pragma unroll
        for (int c = 0; c < 8; ++c){
          f4 wf = *reinterpret_cast<const f4*>(&sW[2*8192 + c*1024 + kxc]);
          float wvv[4] = {wf.x, wf.y, wf.z, wf.w};
          #pragma unroll
          for (int kk = 0; kk < 4; ++kk){
            const f4 sv = sv16[i4*4+kk];
            aH[c][0] = fmaf(wvv[kk], sv.x, aH[c][0]);
            aH[c][1] = fmaf(wvv[kk], sv.y, aH[c][1]);
            aH[c][2] = fmaf(wvv[kk], sv.z, aH[c][2]);
            aH[c][3] = fmaf(wvv[kk], sv.w, aH[c][3]);
          }
        }
      }
      #pragma unroll
      for (int c = 0; c < 8; ++c)
        #pragma unroll
        for (int bb = 0; bb < 4; ++bb) WREDUCE(aH[c][bb]);
      if (wr0)
        #pragma unroll
        for (int c = 0; c < 8; ++c)
          #pragma unroll
          for (int bb = 0; bb < 4; ++bb)
            red[wv*528 + c*32 + bg*4 + bb] = aH[c][bb];
      __syncthreads();
      if (tid < 256){
        float sum = 0.f;
        #pragma unroll
        for (int w = 0; w < 8; ++w) sum += red[w*528 + tid];
        const int c = tid >> 5, bl = tid & 31;
        const float ht = tanhf(sum + xpre[2][tid] + sBias[16 + c]);
        const float z = sZ[tid];
        const float hold = hloc[jrow + c][bl];
        const float hnew = fmaf(z, ht - hold, hold);
        stc1(&h[(j0 + c)*BB + bbase + bl], hnew);
        if (t == TT - 1) out[(size_t)TT*BB*OO + (size_t)(bbase + bl)*HH + j0 + c] = hnew;
      }
      __syncthreads();
      if (tid == 0) g_arrive(bars, bhalf, jt, 2*t + 2);
    }

    // ============ C: x-projections for step t+1 (hides barrier B) ============
    if (t + 1 < TT){
      const int tc = t + 1;
      float aXr[8][4] = {}, aXz[8][4] = {}, aXh[8][4] = {};
      const float* xb = xT + (size_t)tc * II * BB + kx0 * BB + b0;
      #pragma unroll
      for (int i4 = 0; i4 < 2; ++i4){
        f4 xv4[4];
        #pragma unroll
        for (int kk = 0; kk < 4; ++kk) xv4[kk] = ld4(xb + (i4*4+kk) * BB);
        #pragma unroll
        for (int c = 0; c < 8; ++c){
          f4 wr_ = ld4(WxTr + (size_t)(j0 + c) * II + kx0 + i4*4);
          f4 wz_ = ld4(WxTz + (size_t)(j0 + c) * II + kx0 + i4*4);
          f4 wh_ = ld4(WxTh + (size_t)(j0 + c) * II + kx0 + i4*4);
          float wrv[4] = {wr_.x, wr_.y, wr_.z, wr_.w};
          float wzv[4] = {wz_.x, wz_.y, wz_.z, wz_.w};
          float whv[4] = {wh_.x, wh_.y, wh_.z, wh_.w};
          #pragma unroll
          for (int kk = 0; kk < 4; ++kk){
            const f4 xv = xv4[kk];
            aXr[c][0] = fmaf(wrv[kk], xv.x, aXr[c][0]);
            aXr[c][1] = fmaf(wrv[kk], xv.y, aXr[c][1]);
            aXr[c][2] = fmaf(wrv[kk], xv.z, aXr[c][2]);
            aXr[c][3] = fmaf(wrv[kk], xv.w, aXr[c][3]);
            aXz[c][0] = fmaf(wzv[kk], xv.x, aXz[c][0]);
            aXz[c][1] = fmaf(wzv[kk], xv.y, aXz[c][1]);
            aXz[c][2] = fmaf(wzv[kk], xv.z, aXz[c][2]);
            aXz[c][3] = fmaf(wzv[kk], xv.w, aXz[c][3]);
            aXh[c][0] = fmaf(whv[kk], xv.x, aXh[c][0]);
            aXh[c][1] = fmaf(whv[kk], xv.y, aXh[c][1]);
            aXh[c][2] = fmaf(whv[kk], xv.z, aXh[c][2]);
            aXh[c][3] = fmaf(whv[kk], xv.w, aXh[c][3]);
          }
        }
      }
      #pragma unroll
      for (int c = 0; c < 8; ++c)
        #pragma unroll
        for (int bb = 0; bb < 4; ++bb){ WREDUCE(aXr[c][bb]); WREDUCE(aXz[c][bb]); WREDUCE(aXh[c][bb]); }
      if (wr0)
        #pragma unroll
        for (int c = 0; c < 8; ++c)
          #pragma unroll
          for (int bb = 0; bb < 4; ++bb){
            red[wv*528 + c*32 + bg*4 + bb]       = aXr[c][bb];
            red[wv*528 + 256 + c*32 + bg*4 + bb] = aXz[c][bb];
          }
      __syncthreads();
      {
        float sum = 0.f;
        #pragma unroll
        for (int w = 0; w < 8; ++w) sum += red[w*528 + tid];
        if (tid < 256) xpre[0][tid] = sum;
        else           xpre[1][tid - 256] = sum;
      }
      __syncthreads();
      if (wr0)
        #pragma unroll
        for (int c = 0; c < 8; ++c)
          #pragma unroll
          for (int bb = 0; bb < 4; ++bb)
            red[wv*528 + c*32 + bg*4 + bb] = aXh[c][bb];
      __syncthreads();
      if (tid < 256){
        float sum = 0.f;
        #pragma unroll
        for (int w = 0; w < 8; ++w) sum += red[w*528 + tid];
        xpre[2][tid] = sum;
      }
      __syncthreads();
    }

    if (t >= 0){
      if (tid == 0) g_wait(bars, bhalf, 2*t + 2);
      __syncthreads();
    }
  }

  // ================= trailing y_{T-1} from final h =================
  {
    float aY[4][4] = {};
    f4 hv16[16];
    ldc16(h + kh0 * BB + b0, hv16);
    #pragma unroll
    for (int i4 = 0; i4 < 4; ++i4){
      const int kc = kh0 + i4*4;
      #pragma unroll
      for (int oc = 0; oc < 4; ++oc){
        f4 wo = ld4(W_out + (size_t)(o0 + oc) * HH + kc);
        float wvv[4] = {wo.x, wo.y, wo.z, wo.w};
        #pragma unroll
        for (int kk = 0; kk < 4; ++kk){
          const f4 hv = hv16[i4*4+kk];
          aY[oc][0] = fmaf(wvv[kk], hv.x, aY[oc][0]);
          aY[oc][1] = fmaf(wvv[kk], hv.y, aY[oc][1]);
          aY[oc][2] = fmaf(wvv[kk], hv.z, aY[oc][2]);
          aY[oc][3] = fmaf(wvv[kk], hv.w, aY[oc][3]);
        }
      }
    }
    #pragma unroll
    for (int oc = 0; oc < 4; ++oc)
      #pragma unroll
      for (int bb = 0; bb < 4; ++bb) WREDUCE(aY[oc][bb]);
    if (wr0)
      #pragma unroll
      for (int oc = 0; oc < 4; ++oc)
        #pragma unroll
        for (int bb = 0; bb < 4; ++bb)
          red[wv*528 + oc*32 + bg*4 + bb] = aY[oc][bb];
    __syncthreads();
    if (tid < 128){
      float sum = 0.f;
      #pragma unroll
      for (int w = 0; w < 8; ++w) sum += red[w*528 + tid];
      const int oc = tid >> 5, bl = tid & 31;
      out[((size_t)(TT-1)*BB + bbase + bl)*OO + o0 + oc] = sum + sBias[24 + oc];
    }
  }
}

// ---------------- host ----------------
extern "C" void kernel_launch(void* const* d_in, const int* in_sizes, int n_in,
                              void* d_out, int out_size, void* d_ws, size_t ws_size,
                              hipStream_t stream) {
  const float* x     = (const float*)d_in[0];
  const float* st    = (const float*)d_in[1];
  const float* W_zh  = (const float*)d_in[2];
  const float* W_zx  = (const float*)d_in[3];
  const float* b_z   = (const float*)d_in[4];
  const float* W_rh  = (const float*)d_in[5];
  const float* W_rx  = (const float*)d_in[6];
  const float* b_r   = (const float*)d_in[7];
  const float* W_hh  = (const float*)d_in[8];
  const float* W_hx  = (const float*)d_in[9];
  const float* b_h   = (const float*)d_in[10];
  const float* W_out = (const float*)d_in[11];
  const float* b_out = (const float*)d_in[12];
  float* out = (float*)d_out;
  float* ws  = (float*)d_ws;

  const size_t xT_sz = (size_t)TT * II * BB;   // 16,777,216
  const size_t wx_sz = (size_t)II * HH;        //    524,288
  const size_t h_sz  = (size_t)HH * BB;        //     65,536
  const size_t need  = (xT_sz + 3*wx_sz + 2*h_sz) * sizeof(float) + 512*sizeof(unsigned);
  if (ws_size < need) return;

  float* xT   = ws;
  float* WxTr = xT + xT_sz;
  float* WxTz = WxTr + wx_sz;
  float* WxTh = WxTz + wx_sz;
  float* h    = WxTh + wx_sz;
  float* s    = h + h_sz;
  unsigned* bars = (unsigned*)(s + h_sz);

  k_transpose_x <<<8192, 256, 0, stream>>>(x, xT);
  k_transpose_wx<<<2048, 256, 0, stream>>>(W_rx, WxTr);
  k_transpose_wx<<<2048, 256, 0, stream>>>(W_zx, WxTz);
  k_transpose_wx<<<2048, 256, 0, stream>>>(W_hx, WxTh);
  k_transpose_h0<<< 256, 256, 0, stream>>>(st, h);
  k_init_bars   <<<   1, 512, 0, stream>>>(bars);

  k_gru<<<256, NTHR, 0, stream>>>(xT, WxTr, WxTz, WxTh, h, s,
                                  W_zh, b_z, W_rh, b_r, W_hh, b_h,
                                  W_out, b_out, out, bars);
}